// Round 2
// baseline (5615.264 us; speedup 1.0000x reference)
//
#include <hip/hip_runtime.h>
#include <math.h>

#define N 64
#define NPAD 65                   // epilogue LDS stride: conflict-free
#define TRI ((N * (N + 1)) / 2)   // 2080
#define MAX_SWEEPS 20
#define TOL2 1e-10f               // relative off-diag^2 target: rho <= 1e-5

// One wave (64 threads) per matrix. Thread t owns column t of G in registers.
// One-sided Jacobi (Hestenes): right-rotations make columns orthogonal; for
// SPD X the columns converge to u_k * lambda_k, so
//   logm(X) = sum_k log(clip(||g_k||)) / ||g_k||^2 * g_k g_k^T.
// Partner columns are exchanged with __shfl_xor (XOR tournament q = t ^ m
// covers every pair exactly once per sweep; pairs are disjoint per step).
// Convergence-driven: a sweep where every step saw d^2 <= TOL2*na*nb exits.
__global__ __launch_bounds__(64)
void spd_logm_kernel(const float* __restrict__ X, float* __restrict__ out) {
    __shared__ float Gt[N][NPAD];   // epilogue only: Gt[c][r] = column c elem r
    __shared__ float w[N];          // log(s_k)/s_k^2

    const int b = blockIdx.x;
    const int t = threadIdx.x;
    const float* __restrict__ Xb = X + (size_t)b * (N * N);

    // Column t of X: X symmetric, so element k of column t = X[k][t].
    // Lane t, iteration k reads Xb[k*N + t] -> fully coalesced 256B rows.
    float g[N];
    #pragma unroll
    for (int k = 0; k < N; ++k) g[k] = Xb[k * N + t];

    for (int sw = 0; sw < MAX_SWEEPS; ++sw) {
        int bad = 0;
        for (int m = 1; m < N; ++m) {
            const int q = t ^ m;     // disjoint pairs; all pairs once per sweep
            float pt[N];
            float d = 0.f, na = 0.f, nb = 0.f;
            // Partner column via shuffle; dot + both norms in one pass.
            // Both threads of a pair get bit-identical d (commutative fma
            // chain, same order) and consistent (na,nb) via `lower` mapping.
            #pragma unroll
            for (int k = 0; k < N; ++k) {
                const float pv = __shfl_xor(g[k], m, 64);
                pt[k] = pv;
                d  = fmaf(g[k], pv, d);
                na = fmaf(g[k], g[k], na);
                nb = fmaf(pv, pv, nb);
            }
            bad |= (d * d > TOL2 * na * nb);   // fresh measurement, pre-rotation
            const bool lower = (t < q);         // lower index plays "p"
            const float nlo = lower ? na : nb;  // ||g_p||^2
            const float nhi = lower ? nb : na;  // ||g_q||^2
            float c = 1.f, s = 0.f;
            if (fabsf(d) > 1e-36f) {
                // zero (c g_p - s g_q)路(s g_p + c g_q):
                // t^2 + 2 tau t - 1 = 0, tau = (n_q - n_p)/(2 d); inner root
                // => |t|<=1 => |theta|<=pi/4 (required for cyclic convergence)
                const float tau = (nhi - nlo) / (2.f * d);
                const float tt  = copysignf(
                    1.f / (fabsf(tau) + sqrtf(fmaf(tau, tau, 1.f))), tau);
                c = 1.f / sqrtf(fmaf(tt, tt, 1.f));
                s = tt * c;
            }
            const float se = lower ? -s : s;  // p: c*own - s*part ; q: c*own + s*part
            #pragma unroll
            for (int k = 0; k < N; ++k) {
                g[k] = fmaf(se, pt[k], c * g[k]);
            }
        }
        if (!__any(bad)) break;   // full sweep below tol -> converged
    }

    // Stage columns + weights for the output pass.
    float nown = 0.f;
    #pragma unroll
    for (int k = 0; k < N; ++k) {
        Gt[t][k] = g[k];
        nown = fmaf(g[k], g[k], nown);
    }
    float sv = sqrtf(nown);
    sv = fminf(fmaxf(sv, 1e-4f), 1e4f);
    w[t] = logf(sv) / fmaxf(nown, 1e-12f);
    __syncthreads();

    float wr[N];
    #pragma unroll
    for (int k = 0; k < N; ++k) wr[k] = w[k];

    // Upper-triangular output, row-major over j>=i (matches np.triu_indices).
    float* __restrict__ ob = out + (size_t)b * TRI;
    int i = 0;
    int base = 0;
    for (int e = t; e < TRI; e += N) {
        while (base + (N - i) <= e) { base += (N - i); ++i; }
        const int j = i + (e - base);
        float acc = 0.f;
        #pragma unroll
        for (int k = 0; k < N; ++k) {
            // Gt[k][i]: (near-)uniform across lanes -> broadcast;
            // Gt[k][j]: consecutive j across lanes -> conflict-free.
            acc = fmaf(wr[k] * Gt[k][i], Gt[k][j], acc);
        }
        ob[e] = acc;   // consecutive addresses -> coalesced
    }
}

extern "C" void kernel_launch(void* const* d_in, const int* in_sizes, int n_in,
                              void* d_out, int out_size, void* d_ws, size_t ws_size,
                              hipStream_t stream) {
    const float* x = (const float*)d_in[0];
    float* out = (float*)d_out;
    const int B = in_sizes[0] / (N * N);   // 8192
    spd_logm_kernel<<<dim3(B), dim3(64), 0, stream>>>(x, out);
}

// Round 3
// 4204.700 us; speedup vs baseline: 1.3355x; 1.3355x over previous
//
#include <hip/hip_runtime.h>
#include <math.h>

#define N 64
#define TRI ((N * (N + 1)) / 2)   // 2080
#define MAX_SWEEPS 20
#define TOL2 1e-10f               // relative off-diag^2 target: rho <= 1e-5
#define WS_PER_MAT (N * N + N)    // G (row-major) + weight vector, floats

// One-sided Jacobi sweeps. Thread t owns column t of G in g[].
// Column norms are TRACKED: after a rotation with tangent tt,
//   n_p' = n_p - tt*d,  n_q' = n_q + tt*d   (eigenvalues of the 2x2 Gram),
// so the dot loop needs only 1 fma/elem. Tracked norms are refreshed at the
// start of every sweep (drift ~3e-6 rel otherwise; refresh makes it exact).
// Both lanes of a pair compute bit-identical d (commutative fma chain, same
// order) and identical (nlo,nhi) -> identical (c,s,tt): rotation is coherent.
__device__ __forceinline__ void jacobi_sweeps(float g[N]) {
    const int t = threadIdx.x & 63;
    for (int sw = 0; sw < MAX_SWEEPS; ++sw) {
        float na = 0.f;                    // refresh tracked norm
        #pragma unroll
        for (int k = 0; k < N; ++k) na = fmaf(g[k], g[k], na);
        int bad = 0;
        for (int m = 1; m < N; ++m) {
            const int q = t ^ m;           // XOR tournament: disjoint pairs,
            float pt[N];                   // all pairs once per sweep
            float d = 0.f;
            #pragma unroll
            for (int k = 0; k < N; ++k) {
                const float pv = __shfl_xor(g[k], m, 64);
                pt[k] = pv;
                d = fmaf(g[k], pv, d);
            }
            const float nb = __shfl_xor(na, m, 64);   // partner's tracked norm
            bad |= (d * d > TOL2 * na * nb);
            const bool lower = (t < q);     // lower index plays "p"
            const float nlo = lower ? na : nb;
            const float nhi = lower ? nb : na;
            float c = 1.f, s = 0.f, tt = 0.f;
            if (fabsf(d) > 1e-36f) {
                // zero (c g_p - s g_q)·(s g_p + c g_q): t^2 + 2 tau t - 1 = 0,
                // tau = (n_q - n_p)/(2d); inner root -> |theta| <= pi/4
                const float tau = (nhi - nlo) / (2.f * d);
                tt = copysignf(1.f / (fabsf(tau) + sqrtf(fmaf(tau, tau, 1.f))), tau);
                c = 1.f / sqrtf(fmaf(tt, tt, 1.f));
                s = tt * c;
            }
            const float se = lower ? -s : s;
            const float st = lower ? -tt : tt;
            na = fmaf(st, d, na);           // analytic norm update
            #pragma unroll
            for (int k = 0; k < N; ++k) g[k] = fmaf(se, pt[k], c * g[k]);
        }
        if (!__any(bad)) break;             // full sweep below tol
    }
}

// Phase 1: sweeps only, ZERO LDS -> occupancy limited by VGPRs, not LDS.
// Writes G row-major (ws[k*64+t] = elem k of column t, coalesced) + weights.
__global__ __launch_bounds__(64)
void jacobi_kernel(const float* __restrict__ X, float* __restrict__ ws) {
    const int b = blockIdx.x;
    const int t = threadIdx.x;
    const float* __restrict__ Xb = X + (size_t)b * (N * N);
    float g[N];
    #pragma unroll
    for (int k = 0; k < N; ++k) g[k] = Xb[k * N + t];   // coalesced rows
    jacobi_sweeps(g);
    float* __restrict__ wb = ws + (size_t)b * WS_PER_MAT;
    float nown = 0.f;
    #pragma unroll
    for (int k = 0; k < N; ++k) {
        wb[k * N + t] = g[k];
        nown = fmaf(g[k], g[k], nown);
    }
    float sv = sqrtf(nown);
    sv = fminf(fmaxf(sv, 1e-4f), 1e4f);
    wb[N * N + t] = logf(sv) / fmaxf(nown, 1e-12f);     // w_k = log s / s^2
}

// Phase 2: logm[i][j] = sum_t w_t S[i][t] S[j][t], register-tiled 4x4 per
// thread (16 fma per 8 LDS b32 reads), triu-only writes.
__global__ __launch_bounds__(256)
void outer_kernel(const float* __restrict__ ws, float* __restrict__ out) {
    __shared__ float S[N][N + 1];   // S[i][t]; pad -> bank = (i+t)%32
    __shared__ float wv[N];
    const int b = blockIdx.x;
    const int tid = threadIdx.x;
    const float* __restrict__ wb = ws + (size_t)b * WS_PER_MAT;
    for (int idx = tid; idx < N * N; idx += 256)
        S[idx >> 6][idx & 63] = wb[idx];                 // coalesced
    if (tid < N) wv[tid] = wb[N * N + tid];
    __syncthreads();
    const int tx = tid & 15, ty = tid >> 4;
    const int i0 = ty * 4, j0 = tx * 4;                  // 4x4 output tile
    float acc[4][4];
    #pragma unroll
    for (int r = 0; r < 4; ++r)
        #pragma unroll
        for (int c_ = 0; c_ < 4; ++c_) acc[r][c_] = 0.f;
    #pragma unroll 8
    for (int t = 0; t < N; ++t) {
        const float w = wv[t];
        float si[4], sj[4];
        #pragma unroll
        for (int r = 0; r < 4; ++r) si[r] = w * S[i0 + r][t];  // 16 distinct i
        #pragma unroll
        for (int c_ = 0; c_ < 4; ++c_) sj[c_] = S[j0 + c_][t]; // broadcast x4
        #pragma unroll
        for (int r = 0; r < 4; ++r)
            #pragma unroll
            for (int c_ = 0; c_ < 4; ++c_)
                acc[r][c_] = fmaf(si[r], sj[c_], acc[r][c_]);
    }
    // triu row i starts at i*(129-i)/2; entry (i,j) -> start(i) + (j-i)
    float* __restrict__ ob = out + (size_t)b * TRI;
    #pragma unroll
    for (int r = 0; r < 4; ++r) {
        const int i = i0 + r;
        const int st = i * (2 * N + 1 - i) / 2;
        #pragma unroll
        for (int c_ = 0; c_ < 4; ++c_) {
            const int j = j0 + c_;
            if (j >= i) ob[st + (j - i)] = acc[r][c_];
        }
    }
}

// Fallback if ws_size is too small: fused kernel (sweeps + LDS epilogue).
__global__ __launch_bounds__(64)
void fused_kernel(const float* __restrict__ X, float* __restrict__ out) {
    __shared__ float Gt[N][N + 1];
    __shared__ float w[N];
    const int b = blockIdx.x;
    const int t = threadIdx.x;
    const float* __restrict__ Xb = X + (size_t)b * (N * N);
    float g[N];
    #pragma unroll
    for (int k = 0; k < N; ++k) g[k] = Xb[k * N + t];
    jacobi_sweeps(g);
    float nown = 0.f;
    #pragma unroll
    for (int k = 0; k < N; ++k) {
        Gt[t][k] = g[k];
        nown = fmaf(g[k], g[k], nown);
    }
    float sv = sqrtf(nown);
    sv = fminf(fmaxf(sv, 1e-4f), 1e4f);
    w[t] = logf(sv) / fmaxf(nown, 1e-12f);
    __syncthreads();
    float wr[N];
    #pragma unroll
    for (int k = 0; k < N; ++k) wr[k] = w[k];
    float* __restrict__ ob = out + (size_t)b * TRI;
    int i = 0, base = 0;
    for (int e = t; e < TRI; e += N) {
        while (base + (N - i) <= e) { base += (N - i); ++i; }
        const int j = i + (e - base);
        float acc = 0.f;
        #pragma unroll
        for (int k = 0; k < N; ++k)
            acc = fmaf(wr[k] * Gt[k][i], Gt[k][j], acc);
        ob[e] = acc;
    }
}

extern "C" void kernel_launch(void* const* d_in, const int* in_sizes, int n_in,
                              void* d_out, int out_size, void* d_ws, size_t ws_size,
                              hipStream_t stream) {
    const float* x = (const float*)d_in[0];
    float* out = (float*)d_out;
    const int B = in_sizes[0] / (N * N);   // 8192
    const size_t need = (size_t)B * WS_PER_MAT * sizeof(float);  // ~136 MB
    if (ws_size >= need) {
        jacobi_kernel<<<dim3(B), dim3(64), 0, stream>>>(x, (float*)d_ws);
        outer_kernel<<<dim3(B), dim3(256), 0, stream>>>((const float*)d_ws, out);
    } else {
        fused_kernel<<<dim3(B), dim3(64), 0, stream>>>(x, out);
    }
}